// Round 8
// baseline (696.377 us; speedup 1.0000x reference)
//
#include <hip/hip_runtime.h>

typedef unsigned short u16;
typedef signed char s8;
typedef __attribute__((ext_vector_type(8))) short bf16x8;
typedef __attribute__((ext_vector_type(4))) float f32x4;
typedef __attribute__((ext_vector_type(4))) int i32x4;

__device__ __forceinline__ u16 f2bf(float x) {
  unsigned int u = __float_as_uint(x);
  u = u + 0x7FFFu + ((u >> 16) & 1u);
  return (u16)(u >> 16);
}
__device__ __forceinline__ float bf2f(u16 v) {
  return __uint_as_float(((unsigned int)v) << 16);
}

typedef const __attribute__((address_space(1))) void gas_void;
typedef __attribute__((address_space(3))) void las_void;

__device__ __forceinline__ void gld_lds16(const void* g, void* l) {
  __builtin_amdgcn_global_load_lds((gas_void*)g, (las_void*)l, 16, 0, 0);
}

// ---------------- i8 logits GEMM: S = 2*h@cb^T - c_sq via split-2 i8 ----------------
// h = h0/16 + h1/4096 + eps, cb likewise. One fused K-sweep, 3 exact-i32 accumulator sets:
//   M = h0@c0, X = h0@c1 + h1@c0, Y = h1@c1;  S = M*2^-7 + X*2^-15 + Y*2^-23 - c_sq
// Block 128x128, 8 waves (2x4), wave tile 64x32, BK=128 (128B rows), 64KB LDS.
// LDS XOR-swizzle (verified: 0 bank conflicts): stored byte = row*128 + (slot ^ (row&7))*16;
// inverse applied on the global source (gld_lds dest stays linear), same XOR on ds_read.
__global__ __launch_bounds__(512) void gemm_s8(
    const s8* __restrict__ A0, const s8* __restrict__ A1,
    const s8* __restrict__ B0, const s8* __restrict__ B1,
    float* __restrict__ S, const float* __restrict__ c_sq) {
  __shared__ __align__(16) s8 lA0[128 * 128];
  __shared__ __align__(16) s8 lA1[128 * 128];
  __shared__ __align__(16) s8 lB0[128 * 128];
  __shared__ __align__(16) s8 lB1[128 * 128];
  int tid = threadIdx.x, wave = tid >> 6, lane = tid & 63;
  long bm = (long)blockIdx.y * 128, bn = (long)blockIdx.x * 128;
  int wm = (wave >> 2) * 64, wn = (wave & 3) * 32;
  int r15 = lane & 15, kg = lane >> 4;

  i32x4 accM[4][2], accX[4][2], accY[4][2];
#pragma unroll
  for (int i = 0; i < 4; ++i)
#pragma unroll
    for (int j = 0; j < 2; ++j) {
      accM[i][j] = (i32x4){0, 0, 0, 0};
      accX[i][j] = (i32x4){0, 0, 0, 0};
      accY[i][j] = (i32x4){0, 0, 0, 0};
    }

  const s8* a0p = A0 + bm * 1024;
  const s8* a1p = A1 + bm * 1024;
  const s8* b0p = B0 + bn * 1024;
  const s8* b1p = B1 + bn * 1024;

  for (int k0 = 0; k0 < 1024; k0 += 128) {
    __syncthreads();
    // stage 4 x [128][128B] tiles; per array 1024 16B-chunks, 512 threads x 2 rounds
#pragma unroll
    for (int r = 0; r < 2; ++r) {
      int chunk = r * 512 + tid;
      int row = chunk >> 3, slot = chunk & 7;
      int scol = (slot ^ (row & 7)) * 16;       // inverse-swizzled source col (bytes)
      long go = (long)row * 1024 + k0 + scol;
      int ldoff = r * 8192 + wave * 1024;       // + lane*16 by HW
      gld_lds16(a0p + go, lA0 + ldoff);
      gld_lds16(a1p + go, lA1 + ldoff);
      gld_lds16(b0p + go, lB0 + ldoff);
      gld_lds16(b1p + go, lB1 + ldoff);
    }
    __syncthreads();
#pragma unroll
    for (int kk = 0; kk < 2; ++kk) {
      int cb = ((kk * 4 + kg) ^ (r15 & 7)) * 16;
      i32x4 b0f[2], b1f[2];
#pragma unroll
      for (int j = 0; j < 2; ++j) {
        b0f[j] = *(const i32x4*)&lB0[(wn + j * 16 + r15) * 128 + cb];
        b1f[j] = *(const i32x4*)&lB1[(wn + j * 16 + r15) * 128 + cb];
      }
#pragma unroll
      for (int i = 0; i < 4; ++i) {
        i32x4 a0f = *(const i32x4*)&lA0[(wm + i * 16 + r15) * 128 + cb];
        i32x4 a1f = *(const i32x4*)&lA1[(wm + i * 16 + r15) * 128 + cb];
#pragma unroll
        for (int j = 0; j < 2; ++j) {
          accM[i][j] = __builtin_amdgcn_mfma_i32_16x16x64_i8(a0f, b0f[j], accM[i][j], 0, 0, 0);
          accX[i][j] = __builtin_amdgcn_mfma_i32_16x16x64_i8(a0f, b1f[j], accX[i][j], 0, 0, 0);
          accX[i][j] = __builtin_amdgcn_mfma_i32_16x16x64_i8(a1f, b0f[j], accX[i][j], 0, 0, 0);
          accY[i][j] = __builtin_amdgcn_mfma_i32_16x16x64_i8(a1f, b1f[j], accY[i][j], 0, 0, 0);
        }
      }
    }
  }

  // C/D layout: col=lane&15, row=(lane>>4)*4+r
#pragma unroll
  for (int i = 0; i < 4; ++i) {
    long rg = bm + wm + i * 16 + kg * 4;
#pragma unroll
    for (int j = 0; j < 2; ++j) {
      long cg = bn + wn + j * 16 + r15;
      float csq = c_sq[cg];
      i32x4 m = accM[i][j], x = accX[i][j], y = accY[i][j];
#pragma unroll
      for (int r = 0; r < 4; ++r)
        S[(rg + r) * 8192 + cg] = (float)m[r] * 0.0078125f +
                                  (float)x[r] * 3.0517578125e-05f +
                                  (float)y[r] * 1.1920928955078125e-07f - csq;
    }
  }
}

// ---------------- bf16 GEMM, BK=64 (128B rows) + same XOR swizzle ----------------
// MODE 2: C = acc + aux0[m*ldc+n] + aux1[n]   (z_q, f32)
// MODE 3: split-K over blockIdx.z (span KSPAN), bf16 partials (z_e parts)
#define BM 128
#define BN 128
#define BK 64

// stage [128][64] bf16 tile (128B rows), swizzled storage
__device__ __forceinline__ void stage_tile(const u16* __restrict__ src, long lda,
                                           long row0, long k0, u16* ldst,
                                           int wave, int lane) {
  int srow = wave * 8 + (lane >> 3);
  int scol = ((lane & 7) ^ (lane >> 3)) * 8;  // u16 units
#pragma unroll
  for (int c = 0; c < 4; ++c) {
    const u16* g = src + (row0 + c * 32 + srow) * lda + k0 + scol;
    gld_lds16(g, ldst + c * 2048 + wave * 512);
  }
}

template <int MODE>
__global__ __launch_bounds__(256) void gemm_bt(
    const u16* __restrict__ A0, long lda,
    const u16* __restrict__ B0, long ldb,
    void* __restrict__ Cv, long ldc, int KSPAN,
    const float* __restrict__ aux0, const float* __restrict__ aux1, long zstride) {
  __shared__ __align__(16) u16 lA0[BM * BK];
  __shared__ __align__(16) u16 lB0[BN * BK];

  int tid = threadIdx.x;
  int wave = tid >> 6, lane = tid & 63;
  long bm = (long)blockIdx.y * BM, bn = (long)blockIdx.x * BN;
  int wm = (wave >> 1) * 64, wn = (wave & 1) * 64;
  int r15 = lane & 15, kg = lane >> 4;
  long kbase = 0;
  if constexpr (MODE == 3) kbase = (long)blockIdx.z * KSPAN;

  f32x4 acc[4][4];
#pragma unroll
  for (int i = 0; i < 4; ++i)
#pragma unroll
    for (int j = 0; j < 4; ++j) acc[i][j] = (f32x4){0.f, 0.f, 0.f, 0.f};

  for (int k0 = 0; k0 < KSPAN; k0 += BK) {
    __syncthreads();
    stage_tile(A0, lda, bm, kbase + k0, lA0, wave, lane);
    stage_tile(B0, ldb, bn, kbase + k0, lB0, wave, lane);
    __syncthreads();

#pragma unroll
    for (int kk = 0; kk < 2; ++kk) {
      int cu = ((kk * 4 + kg) ^ (r15 & 7)) * 8;  // u16 units
      bf16x8 ah[4], bh[4];
#pragma unroll
      for (int i = 0; i < 4; ++i) {
        ah[i] = *(const bf16x8*)&lA0[(wm + i * 16 + r15) * 64 + cu];
        bh[i] = *(const bf16x8*)&lB0[(wn + i * 16 + r15) * 64 + cu];
      }
#pragma unroll
      for (int i = 0; i < 4; ++i)
#pragma unroll
        for (int j = 0; j < 4; ++j)
          acc[i][j] = __builtin_amdgcn_mfma_f32_16x16x32_bf16(ah[i], bh[j], acc[i][j], 0, 0, 0);
    }
  }

#pragma unroll
  for (int i = 0; i < 4; ++i) {
    long rg = bm + wm + i * 16 + kg * 4;
#pragma unroll
    for (int j = 0; j < 4; ++j) {
      long cg = bn + wn + j * 16 + r15;
      f32x4 v = acc[i][j];
      if constexpr (MODE == 2) {
        float* C = (float*)Cv;
        float bb = aux1[cg];
#pragma unroll
        for (int r = 0; r < 4; ++r)
          C[(rg + r) * ldc + cg] = v[r] + aux0[(rg + r) * ldc + cg] + bb;
      } else {
        u16* P = (u16*)Cv + (long)blockIdx.z * zstride;
#pragma unroll
        for (int r = 0; r < 4; ++r) P[(rg + r) * ldc + cg] = f2bf(v[r]);
      }
    }
  }
}

// ---------------- prep kernels ----------------
__device__ __forceinline__ int quant2(float x) {
  // packed (q0, q1): q0 = round(x*16) in [-127,127]; r = x - q0/16 in [-1/32,1/32];
  // q1 = round(r*4096) clipped to [-127,127]
  float x0 = rintf(x * 16.f);
  x0 = fminf(fmaxf(x0, -127.f), 127.f);
  float x1 = rintf((x - x0 * 0.0625f) * 4096.f);
  x1 = fminf(fmaxf(x1, -127.f), 127.f);
  return ((int)x0 & 0xFF) | (((int)x1 & 0xFF) << 8);
}

__device__ __forceinline__ void quant4(float4 v, unsigned int& w0, unsigned int& w1) {
  int px = quant2(v.x), py = quant2(v.y), pz = quant2(v.z), pw = quant2(v.w);
  w0 = (unsigned int)((px & 0xFF) | ((py & 0xFF) << 8) | ((pz & 0xFF) << 16) |
                      ((pw & 0xFF) << 24));
  w1 = (unsigned int)(((px >> 8) & 0xFF) | (((py >> 8) & 0xFF) << 8) |
                      (((pz >> 8) & 0xFF) << 16) | (((pw >> 8) & 0xFF) << 24));
}

__global__ __launch_bounds__(256) void prep_h_i8(const float* __restrict__ in,
                                                 s8* __restrict__ q0, s8* __restrict__ q1,
                                                 int n4) {
  int i = blockIdx.x * 256 + threadIdx.x;
  if (i >= n4) return;
  float4 v = ((const float4*)in)[i];
  unsigned int w0, w1;
  quant4(v, w0, w1);
  ((unsigned int*)q0)[i] = w0;
  ((unsigned int*)q1)[i] = w1;
}

// one block per codebook row: i8 split + row sum of squares
__global__ __launch_bounds__(256) void prep_cb_i8(const float* __restrict__ cb,
                                                  s8* __restrict__ q0, s8* __restrict__ q1,
                                                  float* __restrict__ c_sq) {
  long k = blockIdx.x;
  int t = threadIdx.x, lane = t & 63, wave = t >> 6;
  float4 v = ((const float4*)(cb + k * 1024))[t];
  unsigned int w0, w1;
  quant4(v, w0, w1);
  ((unsigned int*)(q0 + k * 1024))[t] = w0;
  ((unsigned int*)(q1 + k * 1024))[t] = w1;
  float ss = v.x * v.x + v.y * v.y + v.z * v.z + v.w * v.w;
#pragma unroll
  for (int o = 32; o; o >>= 1) ss += __shfl_xor(ss, o);
  __shared__ float sc[4];
  if (lane == 0) sc[wave] = ss;
  __syncthreads();
  if (t == 0) c_sq[k] = sc[0] + sc[1] + sc[2] + sc[3];
}

__global__ __launch_bounds__(256) void prep_bf16(const float* __restrict__ in,
                                                 u16* __restrict__ o, int n4) {
  int i = blockIdx.x * 256 + threadIdx.x;
  if (i >= n4) return;
  float4 v = ((const float4*)in)[i];
  ushort4 h;
  h.x = f2bf(v.x); h.y = f2bf(v.y); h.z = f2bf(v.z); h.w = f2bf(v.w);
  ((ushort4*)o)[i] = h;
}

// cbT[d][k] = bf16(cb[k][d]);  64x64 tiles
__global__ __launch_bounds__(256) void transpose_cb(const float* __restrict__ cb,
                                                    u16* __restrict__ cbT) {
  __shared__ u16 tt[64][65];
  long k0 = (long)blockIdx.x * 64, d0 = (long)blockIdx.y * 64;
  int t = threadIdx.x;
  int rr = t >> 4, cc = (t & 15) * 4;
#pragma unroll
  for (int p = 0; p < 4; ++p) {
    int r = rr + p * 16;
    float4 v = *(const float4*)(cb + (k0 + r) * 1024 + d0 + cc);
    tt[r][cc] = f2bf(v.x); tt[r][cc + 1] = f2bf(v.y);
    tt[r][cc + 2] = f2bf(v.z); tt[r][cc + 3] = f2bf(v.w);
  }
  __syncthreads();
#pragma unroll
  for (int p = 0; p < 4; ++p) {
    int d = rr + p * 16;
    ushort4 o;
    o.x = tt[cc][d]; o.y = tt[cc + 1][d]; o.z = tt[cc + 2][d]; o.w = tt[cc + 3][d];
    *(ushort4*)(cbT + (d0 + d) * 8192 + k0 + cc) = o;
  }
}

// one block per row of S [8192 floats]; writes q bf16 in-place over row start
__global__ __launch_bounds__(256) void softmax_rows(float* __restrict__ S) {
  long m = blockIdx.x;
  int t = threadIdx.x, lane = t & 63, wave = t >> 6;
  float* row = S + m * 8192;
  float4 v[8];
#pragma unroll
  for (int c = 0; c < 8; ++c) v[c] = ((const float4*)row)[c * 256 + t];
  float mx = -3.0e38f;
#pragma unroll
  for (int c = 0; c < 8; ++c)
    mx = fmaxf(mx, fmaxf(fmaxf(v[c].x, v[c].y), fmaxf(v[c].z, v[c].w)));
#pragma unroll
  for (int o = 32; o; o >>= 1) mx = fmaxf(mx, __shfl_xor(mx, o));
  __shared__ float sc[4];
  if (lane == 0) sc[wave] = mx;
  __syncthreads();
  mx = fmaxf(fmaxf(sc[0], sc[1]), fmaxf(sc[2], sc[3]));
  __syncthreads();
  float sum = 0.f;
#pragma unroll
  for (int c = 0; c < 8; ++c) {
    v[c].x = __expf(v[c].x - mx); v[c].y = __expf(v[c].y - mx);
    v[c].z = __expf(v[c].z - mx); v[c].w = __expf(v[c].w - mx);
    sum += v[c].x + v[c].y + v[c].z + v[c].w;
  }
#pragma unroll
  for (int o = 32; o; o >>= 1) sum += __shfl_xor(sum, o);
  if (lane == 0) sc[wave] = sum;
  __syncthreads();
  float rd = 1.f / (sc[0] + sc[1] + sc[2] + sc[3]);
  u16* q = (u16*)row;
#pragma unroll
  for (int c = 0; c < 8; ++c) {
    ushort4 o;
    o.x = f2bf(v[c].x * rd); o.y = f2bf(v[c].y * rd);
    o.z = f2bf(v[c].z * rd); o.w = f2bf(v[c].w * rd);
    ((ushort4*)q)[c * 256 + t] = o;
  }
}

// per chunk row: z_e = sum of 4 bf16 split-K partials (f32 out),
// then x = RMSNorm(h - z_e) * scale (bf16 out). h/z_e/x pre-offset to chunk.
__global__ __launch_bounds__(256) void reduce_rms(const u16* __restrict__ parts, long rows,
                                                  const float* __restrict__ h,
                                                  const float* __restrict__ scale,
                                                  float* __restrict__ z_e,
                                                  u16* __restrict__ x) {
  long m = blockIdx.x;
  int t = threadIdx.x, lane = t & 63, wave = t >> 6;
  long base = m * 1024 + t * 4;
  long sstride = rows * 1024;
  float4 ze = {0.f, 0.f, 0.f, 0.f};
#pragma unroll
  for (int s = 0; s < 4; ++s) {
    ushort4 p = *(const ushort4*)(parts + s * sstride + base);
    ze.x += bf2f(p.x); ze.y += bf2f(p.y); ze.z += bf2f(p.z); ze.w += bf2f(p.w);
  }
  *(float4*)(z_e + base) = ze;
  float4 hv = *(const float4*)(h + base);
  float4 r;
  r.x = hv.x - ze.x; r.y = hv.y - ze.y; r.z = hv.z - ze.z; r.w = hv.w - ze.w;
  float ss = r.x * r.x + r.y * r.y + r.z * r.z + r.w * r.w;
#pragma unroll
  for (int o = 32; o; o >>= 1) ss += __shfl_xor(ss, o);
  __shared__ float sc[4];
  if (lane == 0) sc[wave] = ss;
  __syncthreads();
  float tot = sc[0] + sc[1] + sc[2] + sc[3];
  float inv = 1.f / (sqrtf(tot * (1.f / 1024.f)) + 1e-8f);
  float4 s4 = *(const float4*)(scale + t * 4);
  ushort4 o;
  o.x = f2bf(r.x * inv * s4.x); o.y = f2bf(r.y * inv * s4.y);
  o.z = f2bf(r.z * inv * s4.z); o.w = f2bf(r.w * inv * s4.w);
  *(ushort4*)(x + base) = o;
}

extern "C" void kernel_launch(void* const* d_in, const int* in_sizes, int n_in,
                              void* d_out, int out_size, void* d_ws, size_t ws_size,
                              hipStream_t stream) {
  const float* h = (const float*)d_in[0];
  const float* cb = (const float*)d_in[1];
  const float* scale = (const float*)d_in[2];
  const float* W = (const float*)d_in[3];
  const float* b = (const float*)d_in[4];
  float* out = (float*)d_out;

  // ws layout: fixed buffers (~98 MB); tail = split-K partials (RC*8KB) + S chunk (RC*32KB)
  char* ws = (char*)d_ws;
  size_t off = 0;
  auto alloc = [&](size_t bytes) -> char* {
    char* p = ws + off;
    off = (off + bytes + 255) & ~(size_t)255;
    return p;
  };
  s8* h0 = (s8*)alloc(8192L * 1024);
  s8* h1 = (s8*)alloc(8192L * 1024);
  s8* c0 = (s8*)alloc(8192L * 1024);
  s8* c1 = (s8*)alloc(8192L * 1024);
  u16* cbT = (u16*)alloc(1024L * 8192 * 2);
  u16* Wbf = (u16*)alloc(1024L * 1024 * 2);
  float* c_sq = (float*)alloc(8192L * 4);
  float* z_e = (float*)alloc(8192L * 1024 * 4);
  u16* x = (u16*)alloc(8192L * 1024 * 2);

  // rows per chunk: each row needs 32768 B (S f32) + 8192 B (4 bf16 partials)
  long RC = 128;
  if (ws_size > off + 128 * 40960L) {
    long cap = (long)((ws_size - off) / 40960L);
    cap = (cap / 128) * 128;
    if (cap > RC) RC = cap;
    if (RC > 8192) RC = 8192;
  }
  u16* parts = (u16*)(ws + off);                        // [4][RC][1024] bf16
  float* S = (float*)(ws + off + (size_t)RC * 8192);    // [RC][8192] f32 (q bf16 in-place)

  prep_h_i8<<<8192, 256, 0, stream>>>(h, h0, h1, 2097152);
  prep_cb_i8<<<8192, 256, 0, stream>>>(cb, c0, c1, c_sq);
  prep_bf16<<<1024, 256, 0, stream>>>(W, Wbf, 262144);
  transpose_cb<<<dim3(128, 16), 256, 0, stream>>>(cb, cbT);

  for (long r0 = 0; r0 < 8192; r0 += RC) {
    long rows = 8192 - r0;
    if (rows > RC) rows = RC;
    // S = 2*h@cb^T - c_sq  via i8 split-2, fused single K-sweep, 128x128 tile
    gemm_s8<<<dim3(64, rows / 128), 512, 0, stream>>>(
        h0 + r0 * 1024, h1 + r0 * 1024, c0, c1, S, c_sq);
    // q = softmax(S) rows, bf16 in-place (row stride 16384 u16)
    softmax_rows<<<rows, 256, 0, stream>>>(S);
    // z_e partials: split-K=4 (span 2048), bf16 partial per z-slice
    gemm_bt<3><<<dim3(8, rows / 128, 4), 256, 0, stream>>>(
        (u16*)S, 16384L, cbT, 8192L,
        parts, 1024L, 2048, nullptr, nullptr, rows * 1024L);
    // z_e = sum(parts); x = RMSNorm(h - z_e)*scale
    reduce_rms<<<rows, 256, 0, stream>>>(parts, rows, h + r0 * 1024, scale,
                                         z_e + r0 * 1024, x + r0 * 1024);
  }

  // out = z_e + x @ W^T + b
  gemm_bt<2><<<dim3(8, 64), 256, 0, stream>>>(x, 1024L, Wbf, 1024L,
                                              out, 1024L, 1024, z_e, b, 0);
}

// Round 9
// 300.952 us; speedup vs baseline: 2.3139x; 2.3139x over previous
//
#include <hip/hip_runtime.h>

typedef unsigned short u16;
typedef __attribute__((ext_vector_type(8))) short bf16x8;
typedef __attribute__((ext_vector_type(4))) float f32x4;

__device__ __forceinline__ u16 f2bf(float x) {
  unsigned int u = __float_as_uint(x);
  u = u + 0x7FFFu + ((u >> 16) & 1u);
  return (u16)(u >> 16);
}
__device__ __forceinline__ float bf2f(u16 v) {
  return __uint_as_float(((unsigned int)v) << 16);
}

typedef const __attribute__((address_space(1))) void gas_void;
typedef __attribute__((address_space(3))) void las_void;

__device__ __forceinline__ void gld_lds16(const void* g, void* l) {
  __builtin_amdgcn_global_load_lds((gas_void*)g, (las_void*)l, 16, 0, 0);
}

#define BM 128
#define BN 128
#define BK 64
#define CAP 512
#define DELTA 32.0f

// ---------------- bf16 GEMM (proven round-7 core, BK=64, XOR swizzle) ----------------
// MODE 2: C(f32) = acc + aux0[m*ldc+n] + aux1[n]              (z_q)
// MODE 4: C(bf16) = csq[n] - 2*acc - 2048                     (coarse dist)
__device__ __forceinline__ void stage_tile(const u16* __restrict__ src, long lda,
                                           long row0, long k0, u16* ldst,
                                           int wave, int lane) {
  int srow = wave * 8 + (lane >> 3);
  int scol = ((lane & 7) ^ (lane >> 3)) * 8;  // u16 units, inverse swizzle on source
#pragma unroll
  for (int c = 0; c < 4; ++c) {
    const u16* g = src + (row0 + c * 32 + srow) * lda + k0 + scol;
    gld_lds16(g, ldst + c * 2048 + wave * 512);
  }
}

template <int MODE>
__global__ __launch_bounds__(256) void gemm_bt(
    const u16* __restrict__ A0, long lda,
    const u16* __restrict__ B0, long ldb,
    void* __restrict__ Cv, long ldc, int K,
    const float* __restrict__ aux0, const float* __restrict__ aux1) {
  __shared__ __align__(16) u16 lA0[BM * BK];
  __shared__ __align__(16) u16 lB0[BN * BK];

  int tid = threadIdx.x;
  int wave = tid >> 6, lane = tid & 63;
  long bm = (long)blockIdx.y * BM, bn = (long)blockIdx.x * BN;
  int wm = (wave >> 1) * 64, wn = (wave & 1) * 64;
  int r15 = lane & 15, kg = lane >> 4;

  f32x4 acc[4][4];
#pragma unroll
  for (int i = 0; i < 4; ++i)
#pragma unroll
    for (int j = 0; j < 4; ++j) acc[i][j] = (f32x4){0.f, 0.f, 0.f, 0.f};

  for (int k0 = 0; k0 < K; k0 += BK) {
    __syncthreads();
    stage_tile(A0, lda, bm, k0, lA0, wave, lane);
    stage_tile(B0, ldb, bn, k0, lB0, wave, lane);
    __syncthreads();

#pragma unroll
    for (int kk = 0; kk < 2; ++kk) {
      int cu = ((kk * 4 + kg) ^ (r15 & 7)) * 8;  // swizzled read col (u16 units)
      bf16x8 ah[4], bh[4];
#pragma unroll
      for (int i = 0; i < 4; ++i) {
        ah[i] = *(const bf16x8*)&lA0[(wm + i * 16 + r15) * 64 + cu];
        bh[i] = *(const bf16x8*)&lB0[(wn + i * 16 + r15) * 64 + cu];
      }
#pragma unroll
      for (int i = 0; i < 4; ++i)
#pragma unroll
        for (int j = 0; j < 4; ++j)
          acc[i][j] = __builtin_amdgcn_mfma_f32_16x16x32_bf16(ah[i], bh[j], acc[i][j], 0, 0, 0);
    }
  }

  // C/D layout: col=lane&15, row=(lane>>4)*4+r
#pragma unroll
  for (int i = 0; i < 4; ++i) {
    long rg = bm + wm + i * 16 + kg * 4;
#pragma unroll
    for (int j = 0; j < 4; ++j) {
      long cg = bn + wn + j * 16 + r15;
      f32x4 v = acc[i][j];
      if constexpr (MODE == 2) {
        float* C = (float*)Cv;
        float bb = aux1[cg];
#pragma unroll
        for (int r = 0; r < 4; ++r)
          C[(rg + r) * ldc + cg] = v[r] + aux0[(rg + r) * ldc + cg] + bb;
      } else {
        u16* P = (u16*)Cv;
        float csq = aux0[cg];
#pragma unroll
        for (int r = 0; r < 4; ++r)
          P[(rg + r) * ldc + cg] = f2bf(csq - 2.f * v[r] - 2048.f);
      }
    }
  }
}

// ---------------- prep kernels ----------------
__global__ __launch_bounds__(256) void prep_bf16(const float* __restrict__ in,
                                                 u16* __restrict__ o, int n4) {
  int i = blockIdx.x * 256 + threadIdx.x;
  if (i >= n4) return;
  float4 v = ((const float4*)in)[i];
  ushort4 h;
  h.x = f2bf(v.x); h.y = f2bf(v.y); h.z = f2bf(v.z); h.w = f2bf(v.w);
  ((ushort4*)o)[i] = h;
}

// one block per codebook row: bf16 cast + row sum of squares (f32)
__global__ __launch_bounds__(256) void prep_cb_bf(const float* __restrict__ cb,
                                                  u16* __restrict__ cbb,
                                                  float* __restrict__ c_sq) {
  long k = blockIdx.x;
  int t = threadIdx.x, lane = t & 63, wave = t >> 6;
  float4 v = ((const float4*)(cb + k * 1024))[t];
  ushort4 hh;
  hh.x = f2bf(v.x); hh.y = f2bf(v.y); hh.z = f2bf(v.z); hh.w = f2bf(v.w);
  ((ushort4*)(cbb + k * 1024))[t] = hh;
  float ss = v.x * v.x + v.y * v.y + v.z * v.z + v.w * v.w;
#pragma unroll
  for (int o = 32; o; o >>= 1) ss += __shfl_xor(ss, o);
  __shared__ float sc[4];
  if (lane == 0) sc[wave] = ss;
  __syncthreads();
  if (t == 0) c_sq[k] = sc[0] + sc[1] + sc[2] + sc[3];
}

// ---------------- candidate scan: per row, min + gather (stored dist <= min+DELTA) ----------------
__global__ __launch_bounds__(256) void scan_rows(const u16* __restrict__ S,
                                                 int* __restrict__ cand,
                                                 int* __restrict__ cnt) {
  long m = blockIdx.x;
  int t = threadIdx.x, lane = t & 63, wave = t >> 6;
  const u16* row = S + m * 8192;
  ushort4 v[8];
#pragma unroll
  for (int i = 0; i < 8; ++i) v[i] = ((const ushort4*)row)[i * 256 + t];  // col = i*1024 + t*4
  float mn = 3.0e38f;
#pragma unroll
  for (int i = 0; i < 8; ++i)
    mn = fminf(mn, fminf(fminf(bf2f(v[i].x), bf2f(v[i].y)),
                         fminf(bf2f(v[i].z), bf2f(v[i].w))));
#pragma unroll
  for (int o = 32; o; o >>= 1) mn = fminf(mn, __shfl_xor(mn, o));
  __shared__ float sm[4];
  __shared__ int wsum[4];
  if (lane == 0) sm[wave] = mn;
  __syncthreads();
  mn = fminf(fminf(sm[0], sm[1]), fminf(sm[2], sm[3]));
  float thr = mn + DELTA;
  int c = 0;
#pragma unroll
  for (int i = 0; i < 8; ++i)
    c += (bf2f(v[i].x) <= thr) + (bf2f(v[i].y) <= thr) +
         (bf2f(v[i].z) <= thr) + (bf2f(v[i].w) <= thr);
  // deterministic ordered compaction: wave inclusive scan + cross-wave offsets
  int pre = c;
#pragma unroll
  for (int o = 1; o < 64; o <<= 1) {
    int y = __shfl_up(pre, o);
    if (lane >= o) pre += y;
  }
  if (lane == 63) wsum[wave] = pre;
  __syncthreads();
  int base = 0;
#pragma unroll
  for (int w = 0; w < 4; ++w) base += (w < wave) ? wsum[w] : 0;
  int pos = base + pre - c;
#pragma unroll
  for (int i = 0; i < 8; ++i) {
    u16 q[4] = {v[i].x, v[i].y, v[i].z, v[i].w};
#pragma unroll
    for (int j = 0; j < 4; ++j) {
      if (bf2f(q[j]) <= thr) {
        if (pos < CAP) cand[m * CAP + pos] = i * 1024 + t * 4 + j;
        ++pos;
      }
    }
  }
  if (t == 0) {
    int tot = wsum[0] + wsum[1] + wsum[2] + wsum[3];
    cnt[m] = tot < CAP ? tot : CAP;
  }
}

// ---------------- refine: exact f32 logits on candidates, softmax, z_e, RMSNorm, x ----------------
__global__ __launch_bounds__(256) void refine_rms(
    const float* __restrict__ h, const float* __restrict__ cb,
    const float* __restrict__ csq, const int* __restrict__ cand,
    const int* __restrict__ cnt, const float* __restrict__ scale,
    float* __restrict__ z_e, u16* __restrict__ x) {
  long m = blockIdx.x;
  int t = threadIdx.x, lane = t & 63, wave = t >> 6;
  int n = cnt[m];
  __shared__ float lg[CAP];
  __shared__ float sc[4];
  const float4* h4 = (const float4*)(h + m * 1024);
  // wave-parallel exact logits: lane owns dims [lane*16, lane*16+16)
  float4 hw[4];
#pragma unroll
  for (int i = 0; i < 4; ++i) hw[i] = h4[lane * 4 + i];
  for (int j = wave; j < n; j += 4) {
    long k = cand[m * CAP + j];
    const float4* c4 = (const float4*)(cb + k * 1024);
    float d = 0.f;
#pragma unroll
    for (int i = 0; i < 4; ++i) {
      float4 cv = c4[lane * 4 + i];
      d += hw[i].x * cv.x + hw[i].y * cv.y + hw[i].z * cv.z + hw[i].w * cv.w;
    }
#pragma unroll
    for (int o = 32; o; o >>= 1) d += __shfl_xor(d, o);
    if (lane == 0) lg[j] = 2.f * d - csq[k];
  }
  __syncthreads();
  // softmax over candidates (every thread computes identical serial result)
  float mx = -3.0e38f;
  for (int j = 0; j < n; ++j) mx = fmaxf(mx, lg[j]);
  float sum = 0.f;
  for (int j = 0; j < n; ++j) sum += __expf(lg[j] - mx);
  float rs = 1.f / sum;
  // z_e: thread owns dims [t*4, t*4+4)
  float4 ze = {0.f, 0.f, 0.f, 0.f};
  for (int j = 0; j < n; ++j) {
    long k = cand[m * CAP + j];
    float w = __expf(lg[j] - mx) * rs;
    float4 cv = ((const float4*)(cb + k * 1024))[t];
    ze.x += w * cv.x; ze.y += w * cv.y; ze.z += w * cv.z; ze.w += w * cv.w;
  }
  *(float4*)(z_e + m * 1024 + t * 4) = ze;
  float4 hv = h4[t];
  float4 r;
  r.x = hv.x - ze.x; r.y = hv.y - ze.y; r.z = hv.z - ze.z; r.w = hv.w - ze.w;
  float ss = r.x * r.x + r.y * r.y + r.z * r.z + r.w * r.w;
#pragma unroll
  for (int o = 32; o; o >>= 1) ss += __shfl_xor(ss, o);
  if (lane == 0) sc[wave] = ss;
  __syncthreads();
  float tot = sc[0] + sc[1] + sc[2] + sc[3];
  float inv = 1.f / (sqrtf(tot * (1.f / 1024.f)) + 1e-8f);
  float4 s4 = ((const float4*)scale)[t];
  ushort4 o;
  o.x = f2bf(r.x * inv * s4.x); o.y = f2bf(r.y * inv * s4.y);
  o.z = f2bf(r.z * inv * s4.z); o.w = f2bf(r.w * inv * s4.w);
  *(ushort4*)(x + m * 1024 + t * 4) = o;
}

extern "C" void kernel_launch(void* const* d_in, const int* in_sizes, int n_in,
                              void* d_out, int out_size, void* d_ws, size_t ws_size,
                              hipStream_t stream) {
  const float* h = (const float*)d_in[0];
  const float* cb = (const float*)d_in[1];
  const float* scale = (const float*)d_in[2];
  const float* W = (const float*)d_in[3];
  const float* b = (const float*)d_in[4];
  float* out = (float*)d_out;

  // ws layout (~226 MB total)
  char* ws = (char*)d_ws;
  size_t off = 0;
  auto alloc = [&](size_t bytes) -> char* {
    char* p = ws + off;
    off = (off + bytes + 255) & ~(size_t)255;
    return p;
  };
  u16* hb = (u16*)alloc(8192L * 1024 * 2);      // h bf16
  u16* cbb = (u16*)alloc(8192L * 1024 * 2);     // cb bf16
  u16* Wbf = (u16*)alloc(1024L * 1024 * 2);     // W bf16
  float* c_sq = (float*)alloc(8192L * 4);
  float* z_e = (float*)alloc(8192L * 1024 * 4); // f32
  u16* x = (u16*)alloc(8192L * 1024 * 2);       // bf16
  int* cand = (int*)alloc(8192L * CAP * 4);     // candidate idx lists
  int* cnt = (int*)alloc(8192L * 4);
  u16* Sbf = (u16*)alloc(8192L * 8192 * 2);     // coarse dist (bf16, offset by 2048)

  prep_bf16<<<8192, 256, 0, stream>>>(h, hb, 2097152);
  prep_cb_bf<<<8192, 256, 0, stream>>>(cb, cbb, c_sq);
  prep_bf16<<<1024, 256, 0, stream>>>(W, Wbf, 262144);

  // coarse dist: Sbf = bf16(csq - 2*h@cb^T - 2048)
  gemm_bt<4><<<dim3(64, 64), 256, 0, stream>>>(hb, 1024L, cbb, 1024L,
                                               Sbf, 8192L, 1024, c_sq, nullptr);
  // per-row min + candidate gather (deterministic ordered compaction)
  scan_rows<<<8192, 256, 0, stream>>>(Sbf, cand, cnt);
  // exact logits on candidates, softmax, z_e (f32), RMSNorm -> x (bf16)
  refine_rms<<<8192, 256, 0, stream>>>(h, cb, c_sq, cand, cnt, scale, z_e, x);
  // out = z_e + x @ W^T + b
  gemm_bt<2><<<dim3(8, 64), 256, 0, stream>>>(x, 1024L, Wbf, 1024L,
                                              out, 1024L, 1024, z_e, b);
}

// Round 10
// 262.453 us; speedup vs baseline: 2.6533x; 1.1467x over previous
//
#include <hip/hip_runtime.h>

typedef unsigned short u16;
typedef signed char s8;
typedef __attribute__((ext_vector_type(8))) short bf16x8;
typedef __attribute__((ext_vector_type(4))) float f32x4;
typedef __attribute__((ext_vector_type(4))) int i32x4;

__device__ __forceinline__ u16 f2bf(float x) {
  unsigned int u = __float_as_uint(x);
  u = u + 0x7FFFu + ((u >> 16) & 1u);
  return (u16)(u >> 16);
}
__device__ __forceinline__ float bf2f(u16 v) {
  return __uint_as_float(((unsigned int)v) << 16);
}

typedef const __attribute__((address_space(1))) void gas_void;
typedef __attribute__((address_space(3))) void las_void;

__device__ __forceinline__ void gld_lds16(const void* g, void* l) {
  __builtin_amdgcn_global_load_lds((gas_void*)g, (las_void*)l, 16, 0, 0);
}

#define BM 128
#define BN 128
#define BK 64
#define CAP 512
#define DELTA 56.0f

// ---------------- i8 coarse dist GEMM (round-7 verified skeleton, 1 acc set) ----------
// S(bf16) = csq[n] - (sum_k qh[m][k]*qc[n][k])/128 - 1024
// Block 128x64, 4 waves (2x2), wave tile 64x32, BK=128 (128B rows), 24KB LDS.
// XOR swizzle (verified 0 conflicts): inverse on global source, same XOR on ds_read.
__global__ __launch_bounds__(256) void gemm_c8(
    const s8* __restrict__ A0, const s8* __restrict__ B0,
    u16* __restrict__ S, const float* __restrict__ c_sq) {
  __shared__ __align__(16) s8 lA[128 * 128];
  __shared__ __align__(16) s8 lB[64 * 128];
  int tid = threadIdx.x, wave = tid >> 6, lane = tid & 63;
  long bm = (long)blockIdx.y * 128, bn = (long)blockIdx.x * 64;
  int wm = (wave >> 1) * 64, wn = (wave & 1) * 32;
  int r15 = lane & 15, kg = lane >> 4;
  int srow = wave * 8 + (lane >> 3);
  int scol = ((lane & 7) ^ (lane >> 3)) * 16;   // inverse-swizzled source col (bytes)

  i32x4 acc[4][2];
#pragma unroll
  for (int i = 0; i < 4; ++i)
#pragma unroll
    for (int j = 0; j < 2; ++j) acc[i][j] = (i32x4){0, 0, 0, 0};

  const s8* ap = A0 + bm * 1024;
  const s8* bp = B0 + bn * 1024;

  for (int k0 = 0; k0 < 1024; k0 += 128) {
    __syncthreads();
#pragma unroll
    for (int c = 0; c < 4; ++c) {
      long go = (long)(c * 32 + srow) * 1024 + k0 + scol;
      gld_lds16(ap + go, lA + c * 4096 + wave * 1024);
    }
#pragma unroll
    for (int c = 0; c < 2; ++c) {
      long go = (long)(c * 32 + srow) * 1024 + k0 + scol;
      gld_lds16(bp + go, lB + c * 4096 + wave * 1024);
    }
    __syncthreads();
#pragma unroll
    for (int kk = 0; kk < 2; ++kk) {
      int cb = ((kk * 4 + kg) ^ (r15 & 7)) * 16;
      i32x4 bf[2];
#pragma unroll
      for (int j = 0; j < 2; ++j)
        bf[j] = *(const i32x4*)&lB[(wn + j * 16 + r15) * 128 + cb];
#pragma unroll
      for (int i = 0; i < 4; ++i) {
        i32x4 af = *(const i32x4*)&lA[(wm + i * 16 + r15) * 128 + cb];
#pragma unroll
        for (int j = 0; j < 2; ++j)
          acc[i][j] = __builtin_amdgcn_mfma_i32_16x16x64_i8(af, bf[j], acc[i][j], 0, 0, 0);
      }
    }
  }

  // C/D layout: col=lane&15, row=(lane>>4)*4+r
#pragma unroll
  for (int i = 0; i < 4; ++i) {
    long rg = bm + wm + i * 16 + kg * 4;
#pragma unroll
    for (int j = 0; j < 2; ++j) {
      long cg = bn + wn + j * 16 + r15;
      float csq = c_sq[cg];
      i32x4 m = acc[i][j];
#pragma unroll
      for (int r = 0; r < 4; ++r)
        S[(rg + r) * 8192 + cg] = f2bf(csq - (float)m[r] * 0.0078125f - 1024.f);
    }
  }
}

// ---------------- bf16 GEMM (round-7 core) MODE 2: C = acc + aux0 + aux1[n] ----------
__device__ __forceinline__ void stage_tile(const u16* __restrict__ src, long lda,
                                           long row0, long k0, u16* ldst,
                                           int wave, int lane) {
  int srow = wave * 8 + (lane >> 3);
  int scol = ((lane & 7) ^ (lane >> 3)) * 8;  // u16 units
#pragma unroll
  for (int c = 0; c < 4; ++c) {
    const u16* g = src + (row0 + c * 32 + srow) * lda + k0 + scol;
    gld_lds16(g, ldst + c * 2048 + wave * 512);
  }
}

__global__ __launch_bounds__(256) void gemm_zq(
    const u16* __restrict__ A0, long lda,
    const u16* __restrict__ B0, long ldb,
    float* __restrict__ C, long ldc, int K,
    const float* __restrict__ aux0, const float* __restrict__ aux1) {
  __shared__ __align__(16) u16 lA0[BM * BK];
  __shared__ __align__(16) u16 lB0[BN * BK];

  int tid = threadIdx.x;
  int wave = tid >> 6, lane = tid & 63;
  long bm = (long)blockIdx.y * BM, bn = (long)blockIdx.x * BN;
  int wm = (wave >> 1) * 64, wn = (wave & 1) * 64;
  int r15 = lane & 15, kg = lane >> 4;

  f32x4 acc[4][4];
#pragma unroll
  for (int i = 0; i < 4; ++i)
#pragma unroll
    for (int j = 0; j < 4; ++j) acc[i][j] = (f32x4){0.f, 0.f, 0.f, 0.f};

  for (int k0 = 0; k0 < K; k0 += BK) {
    __syncthreads();
    stage_tile(A0, lda, bm, k0, lA0, wave, lane);
    stage_tile(B0, ldb, bn, k0, lB0, wave, lane);
    __syncthreads();

#pragma unroll
    for (int kk = 0; kk < 2; ++kk) {
      int cu = ((kk * 4 + kg) ^ (r15 & 7)) * 8;
      bf16x8 ah[4], bh[4];
#pragma unroll
      for (int i = 0; i < 4; ++i) {
        ah[i] = *(const bf16x8*)&lA0[(wm + i * 16 + r15) * 64 + cu];
        bh[i] = *(const bf16x8*)&lB0[(wn + i * 16 + r15) * 64 + cu];
      }
#pragma unroll
      for (int i = 0; i < 4; ++i)
#pragma unroll
        for (int j = 0; j < 4; ++j)
          acc[i][j] = __builtin_amdgcn_mfma_f32_16x16x32_bf16(ah[i], bh[j], acc[i][j], 0, 0, 0);
    }
  }

#pragma unroll
  for (int i = 0; i < 4; ++i) {
    long rg = bm + wm + i * 16 + kg * 4;
#pragma unroll
    for (int j = 0; j < 4; ++j) {
      long cg = bn + wn + j * 16 + r15;
      f32x4 v = acc[i][j];
      float bb = aux1[cg];
#pragma unroll
      for (int r = 0; r < 4; ++r)
        C[(rg + r) * ldc + cg] = v[r] + aux0[(rg + r) * ldc + cg] + bb;
    }
  }
}

// ---------------- prep kernels ----------------
__device__ __forceinline__ int q8(float x) {
  float q = rintf(x * 16.f);
  q = fminf(fmaxf(q, -127.f), 127.f);
  return (int)q;
}

__global__ __launch_bounds__(256) void prep_h_i8(const float* __restrict__ in,
                                                 s8* __restrict__ q0, int n4) {
  int i = blockIdx.x * 256 + threadIdx.x;
  if (i >= n4) return;
  float4 v = ((const float4*)in)[i];
  unsigned int w = (unsigned int)((q8(v.x) & 0xFF) | ((q8(v.y) & 0xFF) << 8) |
                                  ((q8(v.z) & 0xFF) << 16) | ((q8(v.w) & 0xFF) << 24));
  ((unsigned int*)q0)[i] = w;
}

// one block per codebook row: i8 quant + row sum of squares (f32)
__global__ __launch_bounds__(256) void prep_cb_i8(const float* __restrict__ cb,
                                                  s8* __restrict__ q0,
                                                  float* __restrict__ c_sq) {
  long k = blockIdx.x;
  int t = threadIdx.x, lane = t & 63, wave = t >> 6;
  float4 v = ((const float4*)(cb + k * 1024))[t];
  unsigned int w = (unsigned int)((q8(v.x) & 0xFF) | ((q8(v.y) & 0xFF) << 8) |
                                  ((q8(v.z) & 0xFF) << 16) | ((q8(v.w) & 0xFF) << 24));
  ((unsigned int*)(q0 + k * 1024))[t] = w;
  float ss = v.x * v.x + v.y * v.y + v.z * v.z + v.w * v.w;
#pragma unroll
  for (int o = 32; o; o >>= 1) ss += __shfl_xor(ss, o);
  __shared__ float sc[4];
  if (lane == 0) sc[wave] = ss;
  __syncthreads();
  if (t == 0) c_sq[k] = sc[0] + sc[1] + sc[2] + sc[3];
}

__global__ __launch_bounds__(256) void prep_bf16(const float* __restrict__ in,
                                                 u16* __restrict__ o, int n4) {
  int i = blockIdx.x * 256 + threadIdx.x;
  if (i >= n4) return;
  float4 v = ((const float4*)in)[i];
  ushort4 h;
  h.x = f2bf(v.x); h.y = f2bf(v.y); h.z = f2bf(v.z); h.w = f2bf(v.w);
  ((ushort4*)o)[i] = h;
}

// ---------------- candidate scan: per row, min + gather (stored dist <= min+DELTA) ----
__global__ __launch_bounds__(256) void scan_rows(const u16* __restrict__ S,
                                                 int* __restrict__ cand,
                                                 int* __restrict__ cnt) {
  long m = blockIdx.x;
  int t = threadIdx.x, lane = t & 63, wave = t >> 6;
  const u16* row = S + m * 8192;
  ushort4 v[8];
#pragma unroll
  for (int i = 0; i < 8; ++i) v[i] = ((const ushort4*)row)[i * 256 + t];  // col = i*1024 + t*4
  float mn = 3.0e38f;
#pragma unroll
  for (int i = 0; i < 8; ++i)
    mn = fminf(mn, fminf(fminf(bf2f(v[i].x), bf2f(v[i].y)),
                         fminf(bf2f(v[i].z), bf2f(v[i].w))));
#pragma unroll
  for (int o = 32; o; o >>= 1) mn = fminf(mn, __shfl_xor(mn, o));
  __shared__ float sm[4];
  __shared__ int wsum[4];
  if (lane == 0) sm[wave] = mn;
  __syncthreads();
  mn = fminf(fminf(sm[0], sm[1]), fminf(sm[2], sm[3]));
  float thr = mn + DELTA;
  int c = 0;
#pragma unroll
  for (int i = 0; i < 8; ++i)
    c += (bf2f(v[i].x) <= thr) + (bf2f(v[i].y) <= thr) +
         (bf2f(v[i].z) <= thr) + (bf2f(v[i].w) <= thr);
  // deterministic ordered compaction: wave inclusive scan + cross-wave offsets
  int pre = c;
#pragma unroll
  for (int o = 1; o < 64; o <<= 1) {
    int y = __shfl_up(pre, o);
    if (lane >= o) pre += y;
  }
  if (lane == 63) wsum[wave] = pre;
  __syncthreads();
  int base = 0;
#pragma unroll
  for (int w = 0; w < 4; ++w) base += (w < wave) ? wsum[w] : 0;
  int pos = base + pre - c;
#pragma unroll
  for (int i = 0; i < 8; ++i) {
    u16 q[4] = {v[i].x, v[i].y, v[i].z, v[i].w};
#pragma unroll
    for (int j = 0; j < 4; ++j) {
      if (bf2f(q[j]) <= thr) {
        if (pos < CAP) cand[m * CAP + pos] = i * 1024 + t * 4 + j;
        ++pos;
      }
    }
  }
  if (t == 0) {
    int tot = wsum[0] + wsum[1] + wsum[2] + wsum[3];
    cnt[m] = tot < CAP ? tot : CAP;
  }
}

// ---------------- refine: exact f32 logits on candidates, softmax, z_e, RMSNorm, x ----
__global__ __launch_bounds__(256) void refine_rms(
    const float* __restrict__ h, const float* __restrict__ cb,
    const float* __restrict__ csq, const int* __restrict__ cand,
    const int* __restrict__ cnt, const float* __restrict__ scale,
    float* __restrict__ z_e, u16* __restrict__ x) {
  long m = blockIdx.x;
  int t = threadIdx.x, lane = t & 63, wave = t >> 6;
  int n = cnt[m];
  __shared__ float lg[CAP];
  __shared__ float sc[4];
  const float4* h4 = (const float4*)(h + m * 1024);
  // wave-parallel exact logits: lane owns dims [lane*16, lane*16+16)
  float4 hw[4];
#pragma unroll
  for (int i = 0; i < 4; ++i) hw[i] = h4[lane * 4 + i];
  for (int j = wave; j < n; j += 4) {
    long k = cand[m * CAP + j];
    const float4* c4 = (const float4*)(cb + k * 1024);
    float d = 0.f;
#pragma unroll
    for (int i = 0; i < 4; ++i) {
      float4 cv = c4[lane * 4 + i];
      d += hw[i].x * cv.x + hw[i].y * cv.y + hw[i].z * cv.z + hw[i].w * cv.w;
    }
#pragma unroll
    for (int o = 32; o; o >>= 1) d += __shfl_xor(d, o);
    if (lane == 0) lg[j] = 2.f * d - csq[k];
  }
  __syncthreads();
  // softmax over candidates (every thread computes identical serial result)
  float mx = -3.0e38f;
  for (int j = 0; j < n; ++j) mx = fmaxf(mx, lg[j]);
  float sum = 0.f;
  for (int j = 0; j < n; ++j) sum += __expf(lg[j] - mx);
  float rs = 1.f / sum;
  // z_e: thread owns dims [t*4, t*4+4)
  float4 ze = {0.f, 0.f, 0.f, 0.f};
  for (int j = 0; j < n; ++j) {
    long k = cand[m * CAP + j];
    float w = __expf(lg[j] - mx) * rs;
    float4 cv = ((const float4*)(cb + k * 1024))[t];
    ze.x += w * cv.x; ze.y += w * cv.y; ze.z += w * cv.z; ze.w += w * cv.w;
  }
  *(float4*)(z_e + m * 1024 + t * 4) = ze;
  float4 hv = h4[t];
  float4 r;
  r.x = hv.x - ze.x; r.y = hv.y - ze.y; r.z = hv.z - ze.z; r.w = hv.w - ze.w;
  float ss = r.x * r.x + r.y * r.y + r.z * r.z + r.w * r.w;
#pragma unroll
  for (int o = 32; o; o >>= 1) ss += __shfl_xor(ss, o);
  if (lane == 0) sc[wave] = ss;
  __syncthreads();
  float tot = sc[0] + sc[1] + sc[2] + sc[3];
  float inv = 1.f / (sqrtf(tot * (1.f / 1024.f)) + 1e-8f);
  float4 s4 = ((const float4*)scale)[t];
  ushort4 o;
  o.x = f2bf(r.x * inv * s4.x); o.y = f2bf(r.y * inv * s4.y);
  o.z = f2bf(r.z * inv * s4.z); o.w = f2bf(r.w * inv * s4.w);
  *(ushort4*)(x + m * 1024 + t * 4) = o;
}

extern "C" void kernel_launch(void* const* d_in, const int* in_sizes, int n_in,
                              void* d_out, int out_size, void* d_ws, size_t ws_size,
                              hipStream_t stream) {
  const float* h = (const float*)d_in[0];
  const float* cb = (const float*)d_in[1];
  const float* scale = (const float*)d_in[2];
  const float* W = (const float*)d_in[3];
  const float* b = (const float*)d_in[4];
  float* out = (float*)d_out;

  // ws layout (~210 MB total)
  char* ws = (char*)d_ws;
  size_t off = 0;
  auto alloc = [&](size_t bytes) -> char* {
    char* p = ws + off;
    off = (off + bytes + 255) & ~(size_t)255;
    return p;
  };
  s8* h8 = (s8*)alloc(8192L * 1024);            // h i8 (x16)
  s8* c8 = (s8*)alloc(8192L * 1024);            // cb i8 (x16)
  u16* Wbf = (u16*)alloc(1024L * 1024 * 2);     // W bf16
  float* c_sq = (float*)alloc(8192L * 4);
  float* z_e = (float*)alloc(8192L * 1024 * 4); // f32
  u16* x = (u16*)alloc(8192L * 1024 * 2);       // bf16
  int* cand = (int*)alloc(8192L * CAP * 4);     // candidate idx lists
  int* cnt = (int*)alloc(8192L * 4);
  u16* Sbf = (u16*)alloc(8192L * 8192 * 2);     // coarse dist (bf16, offset by 1024)

  prep_h_i8<<<8192, 256, 0, stream>>>(h, h8, 2097152);
  prep_cb_i8<<<8192, 256, 0, stream>>>(cb, c8, c_sq);
  prep_bf16<<<1024, 256, 0, stream>>>(W, Wbf, 262144);

  // coarse dist via i8 MFMA: Sbf = bf16(csq - qh@qc/128 - 1024)
  gemm_c8<<<dim3(128, 64), 256, 0, stream>>>(h8, c8, Sbf, c_sq);
  // per-row min + candidate gather (deterministic ordered compaction)
  scan_rows<<<8192, 256, 0, stream>>>(Sbf, cand, cnt);
  // exact logits on candidates, softmax, z_e (f32), RMSNorm -> x (bf16)
  refine_rms<<<8192, 256, 0, stream>>>(h, cb, c_sq, cand, cnt, scale, z_e, x);
  // out = z_e + x @ W^T + b
  gemm_zq<<<dim3(8, 64), 256, 0, stream>>>(x, 1024L, Wbf, 1024L,
                                           out, 1024L, 1024, z_e, b);
}

// Round 11
// 227.377 us; speedup vs baseline: 3.0626x; 1.1543x over previous
//
#include <hip/hip_runtime.h>

typedef unsigned short u16;
typedef signed char s8;
typedef __attribute__((ext_vector_type(8))) short bf16x8;
typedef __attribute__((ext_vector_type(4))) float f32x4;
typedef __attribute__((ext_vector_type(4))) int i32x4;

__device__ __forceinline__ u16 f2bf(float x) {
  unsigned int u = __float_as_uint(x);
  u = u + 0x7FFFu + ((u >> 16) & 1u);
  return (u16)(u >> 16);
}
__device__ __forceinline__ float bf2f(u16 v) {
  return __uint_as_float(((unsigned int)v) << 16);
}

typedef const __attribute__((address_space(1))) void gas_void;
typedef __attribute__((address_space(3))) void las_void;

__device__ __forceinline__ void gld_lds16(const void* g, void* l) {
  __builtin_amdgcn_global_load_lds((gas_void*)g, (las_void*)l, 16, 0, 0);
}

#define BM 128
#define BN 128
#define BK 64
#define CAP 512
#define DELTA 56.0f

// ---------------- i8 coarse dist GEMM: 128x128 tile, 4 waves (2x2), wave 64x64 ------
// S(bf16) = csq[n] - (sum_k qh[m][k]*qc[n][k])/128 - 1024
// BK=128 (128B rows), 32KB LDS. XOR swizzle (verified 0 conflicts):
// inverse on global source (gld_lds dest linear), same XOR on ds_read.
__global__ __launch_bounds__(256) void gemm_c8(
    const s8* __restrict__ A0, const s8* __restrict__ B0,
    u16* __restrict__ S, const float* __restrict__ c_sq) {
  __shared__ __align__(16) s8 lA[128 * 128];
  __shared__ __align__(16) s8 lB[128 * 128];
  int tid = threadIdx.x, wave = tid >> 6, lane = tid & 63;
  long bm = (long)blockIdx.y * 128, bn = (long)blockIdx.x * 128;
  int wm = (wave >> 1) * 64, wn = (wave & 1) * 64;
  int r15 = lane & 15, kg = lane >> 4;
  int srow = wave * 8 + (lane >> 3);
  int scol = ((lane & 7) ^ (lane >> 3)) * 16;   // inverse-swizzled source col (bytes)

  i32x4 acc[4][4];
#pragma unroll
  for (int i = 0; i < 4; ++i)
#pragma unroll
    for (int j = 0; j < 4; ++j) acc[i][j] = (i32x4){0, 0, 0, 0};

  const s8* ap = A0 + bm * 1024;
  const s8* bp = B0 + bn * 1024;

  for (int k0 = 0; k0 < 1024; k0 += 128) {
    __syncthreads();
#pragma unroll
    for (int c = 0; c < 4; ++c) {
      long go = (long)(c * 32 + srow) * 1024 + k0 + scol;
      int ldoff = c * 4096 + wave * 1024;  // + lane*16 by HW
      gld_lds16(ap + go, lA + ldoff);
      gld_lds16(bp + go, lB + ldoff);
    }
    __syncthreads();
#pragma unroll
    for (int kk = 0; kk < 2; ++kk) {
      int cb = ((kk * 4 + kg) ^ (r15 & 7)) * 16;
      i32x4 bf[4];
#pragma unroll
      for (int j = 0; j < 4; ++j)
        bf[j] = *(const i32x4*)&lB[(wn + j * 16 + r15) * 128 + cb];
#pragma unroll
      for (int i = 0; i < 4; ++i) {
        i32x4 af = *(const i32x4*)&lA[(wm + i * 16 + r15) * 128 + cb];
#pragma unroll
        for (int j = 0; j < 4; ++j)
          acc[i][j] = __builtin_amdgcn_mfma_i32_16x16x64_i8(af, bf[j], acc[i][j], 0, 0, 0);
      }
    }
  }

  // C/D layout: col=lane&15, row=(lane>>4)*4+r
#pragma unroll
  for (int i = 0; i < 4; ++i) {
    long rg = bm + wm + i * 16 + kg * 4;
#pragma unroll
    for (int j = 0; j < 4; ++j) {
      long cg = bn + wn + j * 16 + r15;
      float csq = c_sq[cg];
      i32x4 m = acc[i][j];
#pragma unroll
      for (int r = 0; r < 4; ++r)
        S[(rg + r) * 8192 + cg] = f2bf(csq - (float)m[r] * 0.0078125f - 1024.f);
    }
  }
}

// ---------------- bf16 GEMM (round-7 core): C = acc + aux0 + aux1[n] ----------------
__device__ __forceinline__ void stage_tile(const u16* __restrict__ src, long lda,
                                           long row0, long k0, u16* ldst,
                                           int wave, int lane) {
  int srow = wave * 8 + (lane >> 3);
  int scol = ((lane & 7) ^ (lane >> 3)) * 8;  // u16 units
#pragma unroll
  for (int c = 0; c < 4; ++c) {
    const u16* g = src + (row0 + c * 32 + srow) * lda + k0 + scol;
    gld_lds16(g, ldst + c * 2048 + wave * 512);
  }
}

__global__ __launch_bounds__(256) void gemm_zq(
    const u16* __restrict__ A0, long lda,
    const u16* __restrict__ B0, long ldb,
    float* __restrict__ C, long ldc, int K,
    const float* __restrict__ aux0, const float* __restrict__ aux1) {
  __shared__ __align__(16) u16 lA0[BM * BK];
  __shared__ __align__(16) u16 lB0[BN * BK];

  int tid = threadIdx.x;
  int wave = tid >> 6, lane = tid & 63;
  long bm = (long)blockIdx.y * BM, bn = (long)blockIdx.x * BN;
  int wm = (wave >> 1) * 64, wn = (wave & 1) * 64;
  int r15 = lane & 15, kg = lane >> 4;

  f32x4 acc[4][4];
#pragma unroll
  for (int i = 0; i < 4; ++i)
#pragma unroll
    for (int j = 0; j < 4; ++j) acc[i][j] = (f32x4){0.f, 0.f, 0.f, 0.f};

  for (int k0 = 0; k0 < K; k0 += BK) {
    __syncthreads();
    stage_tile(A0, lda, bm, k0, lA0, wave, lane);
    stage_tile(B0, ldb, bn, k0, lB0, wave, lane);
    __syncthreads();

#pragma unroll
    for (int kk = 0; kk < 2; ++kk) {
      int cu = ((kk * 4 + kg) ^ (r15 & 7)) * 8;
      bf16x8 ah[4], bh[4];
#pragma unroll
      for (int i = 0; i < 4; ++i) {
        ah[i] = *(const bf16x8*)&lA0[(wm + i * 16 + r15) * 64 + cu];
        bh[i] = *(const bf16x8*)&lB0[(wn + i * 16 + r15) * 64 + cu];
      }
#pragma unroll
      for (int i = 0; i < 4; ++i)
#pragma unroll
        for (int j = 0; j < 4; ++j)
          acc[i][j] = __builtin_amdgcn_mfma_f32_16x16x32_bf16(ah[i], bh[j], acc[i][j], 0, 0, 0);
    }
  }

#pragma unroll
  for (int i = 0; i < 4; ++i) {
    long rg = bm + wm + i * 16 + kg * 4;
#pragma unroll
    for (int j = 0; j < 4; ++j) {
      long cg = bn + wn + j * 16 + r15;
      f32x4 v = acc[i][j];
      float bb = aux1[cg];
#pragma unroll
      for (int r = 0; r < 4; ++r)
        C[(rg + r) * ldc + cg] = v[r] + aux0[(rg + r) * ldc + cg] + bb;
    }
  }
}

// ---------------- prep kernels ----------------
__device__ __forceinline__ int q8(float x) {
  float q = rintf(x * 16.f);
  q = fminf(fmaxf(q, -127.f), 127.f);
  return (int)q;
}

__global__ __launch_bounds__(256) void prep_h_i8(const float* __restrict__ in,
                                                 s8* __restrict__ q0, int n4) {
  int i = blockIdx.x * 256 + threadIdx.x;
  if (i >= n4) return;
  float4 v = ((const float4*)in)[i];
  unsigned int w = (unsigned int)((q8(v.x) & 0xFF) | ((q8(v.y) & 0xFF) << 8) |
                                  ((q8(v.z) & 0xFF) << 16) | ((q8(v.w) & 0xFF) << 24));
  ((unsigned int*)q0)[i] = w;
}

__global__ __launch_bounds__(256) void prep_cb_i8(const float* __restrict__ cb,
                                                  s8* __restrict__ q0,
                                                  float* __restrict__ c_sq) {
  long k = blockIdx.x;
  int t = threadIdx.x, lane = t & 63, wave = t >> 6;
  float4 v = ((const float4*)(cb + k * 1024))[t];
  unsigned int w = (unsigned int)((q8(v.x) & 0xFF) | ((q8(v.y) & 0xFF) << 8) |
                                  ((q8(v.z) & 0xFF) << 16) | ((q8(v.w) & 0xFF) << 24));
  ((unsigned int*)(q0 + k * 1024))[t] = w;
  float ss = v.x * v.x + v.y * v.y + v.z * v.z + v.w * v.w;
#pragma unroll
  for (int o = 32; o; o >>= 1) ss += __shfl_xor(ss, o);
  __shared__ float sc[4];
  if (lane == 0) sc[wave] = ss;
  __syncthreads();
  if (t == 0) c_sq[k] = sc[0] + sc[1] + sc[2] + sc[3];
}

__global__ __launch_bounds__(256) void prep_bf16(const float* __restrict__ in,
                                                 u16* __restrict__ o, int n4) {
  int i = blockIdx.x * 256 + threadIdx.x;
  if (i >= n4) return;
  float4 v = ((const float4*)in)[i];
  ushort4 h;
  h.x = f2bf(v.x); h.y = f2bf(v.y); h.z = f2bf(v.z); h.w = f2bf(v.w);
  ((ushort4*)o)[i] = h;
}

// ---------------- candidate scan: per row, min + gather (stored dist <= min+DELTA) ----
__global__ __launch_bounds__(256) void scan_rows(const u16* __restrict__ S,
                                                 int* __restrict__ cand,
                                                 int* __restrict__ cnt) {
  long m = blockIdx.x;
  int t = threadIdx.x, lane = t & 63, wave = t >> 6;
  const u16* row = S + m * 8192;
  ushort4 v[8];
#pragma unroll
  for (int i = 0; i < 8; ++i) v[i] = ((const ushort4*)row)[i * 256 + t];  // col = i*1024 + t*4
  float mn = 3.0e38f;
#pragma unroll
  for (int i = 0; i < 8; ++i)
    mn = fminf(mn, fminf(fminf(bf2f(v[i].x), bf2f(v[i].y)),
                         fminf(bf2f(v[i].z), bf2f(v[i].w))));
#pragma unroll
  for (int o = 32; o; o >>= 1) mn = fminf(mn, __shfl_xor(mn, o));
  __shared__ float sm[4];
  __shared__ int wsum[4];
  if (lane == 0) sm[wave] = mn;
  __syncthreads();
  mn = fminf(fminf(sm[0], sm[1]), fminf(sm[2], sm[3]));
  float thr = mn + DELTA;
  int c = 0;
#pragma unroll
  for (int i = 0; i < 8; ++i)
    c += (bf2f(v[i].x) <= thr) + (bf2f(v[i].y) <= thr) +
         (bf2f(v[i].z) <= thr) + (bf2f(v[i].w) <= thr);
  // deterministic ordered compaction: wave inclusive scan + cross-wave offsets
  int pre = c;
#pragma unroll
  for (int o = 1; o < 64; o <<= 1) {
    int y = __shfl_up(pre, o);
    if (lane >= o) pre += y;
  }
  if (lane == 63) wsum[wave] = pre;
  __syncthreads();
  int base = 0;
#pragma unroll
  for (int w = 0; w < 4; ++w) base += (w < wave) ? wsum[w] : 0;
  int pos = base + pre - c;
#pragma unroll
  for (int i = 0; i < 8; ++i) {
    u16 q[4] = {v[i].x, v[i].y, v[i].z, v[i].w};
#pragma unroll
    for (int j = 0; j < 4; ++j) {
      if (bf2f(q[j]) <= thr) {
        if (pos < CAP) cand[m * CAP + pos] = i * 1024 + t * 4 + j;
        ++pos;
      }
    }
  }
  if (t == 0) {
    int tot = wsum[0] + wsum[1] + wsum[2] + wsum[3];
    cnt[m] = tot < CAP ? tot : CAP;
  }
}

// ---------------- refine: single-pass online softmax + z_e + RMSNorm ----------------
// Wave w handles candidates j = w, w+4, ... Lane owns dims [lane*16, lane*16+16).
// One row read feeds both the exact f32 dot and the weighted accumulator.
__global__ __launch_bounds__(256) void refine_rms(
    const float* __restrict__ h, const float* __restrict__ cb,
    const float* __restrict__ csq, const int* __restrict__ cand,
    const int* __restrict__ cnt, const float* __restrict__ scale,
    float* __restrict__ z_e, u16* __restrict__ x) {
  long m = blockIdx.x;
  int t = threadIdx.x, lane = t & 63, wave = t >> 6;
  int n = cnt[m];
  __shared__ float sm[4], ssum[4], sc[4];
  __shared__ float lacc[4][1024];  // 16KB, per-wave partial z_e (unnormalized)
  const float4* h4 = (const float4*)(h + m * 1024);
  float4 hw[4];
#pragma unroll
  for (int i = 0; i < 4; ++i) hw[i] = h4[lane * 4 + i];

  float mw = -3.0e38f, sw = 0.f;
  float4 a0 = {0.f, 0.f, 0.f, 0.f}, a1 = a0, a2 = a0, a3 = a0;
  for (int j = wave; j < n; j += 4) {
    long k = cand[m * CAP + j];
    const float4* c4 = (const float4*)(cb + k * 1024);
    float4 cv0 = c4[lane * 4 + 0], cv1 = c4[lane * 4 + 1];
    float4 cv2 = c4[lane * 4 + 2], cv3 = c4[lane * 4 + 3];
    float d = hw[0].x * cv0.x + hw[0].y * cv0.y + hw[0].z * cv0.z + hw[0].w * cv0.w +
              hw[1].x * cv1.x + hw[1].y * cv1.y + hw[1].z * cv1.z + hw[1].w * cv1.w +
              hw[2].x * cv2.x + hw[2].y * cv2.y + hw[2].z * cv2.z + hw[2].w * cv2.w +
              hw[3].x * cv3.x + hw[3].y * cv3.y + hw[3].z * cv3.z + hw[3].w * cv3.w;
#pragma unroll
    for (int o = 32; o; o >>= 1) d += __shfl_xor(d, o);
    float lg = 2.f * d - csq[k];
    if (lg > mw) {
      float r = __expf(mw - lg);
      sw *= r;
      a0.x *= r; a0.y *= r; a0.z *= r; a0.w *= r;
      a1.x *= r; a1.y *= r; a1.z *= r; a1.w *= r;
      a2.x *= r; a2.y *= r; a2.z *= r; a2.w *= r;
      a3.x *= r; a3.y *= r; a3.z *= r; a3.w *= r;
      mw = lg;
    }
    float w = __expf(lg - mw);
    sw += w;
    a0.x += w * cv0.x; a0.y += w * cv0.y; a0.z += w * cv0.z; a0.w += w * cv0.w;
    a1.x += w * cv1.x; a1.y += w * cv1.y; a1.z += w * cv1.z; a1.w += w * cv1.w;
    a2.x += w * cv2.x; a2.y += w * cv2.y; a2.z += w * cv2.z; a2.w += w * cv2.w;
    a3.x += w * cv3.x; a3.y += w * cv3.y; a3.z += w * cv3.z; a3.w += w * cv3.w;
  }
  if (lane == 0) { sm[wave] = mw; ssum[wave] = sw; }
  __syncthreads();
  float M = fmaxf(fmaxf(sm[0], sm[1]), fmaxf(sm[2], sm[3]));
  float Stot = ssum[0] * __expf(sm[0] - M) + ssum[1] * __expf(sm[1] - M) +
               ssum[2] * __expf(sm[2] - M) + ssum[3] * __expf(sm[3] - M);
  float rw = __expf(mw - M);
  float* lw = &lacc[wave][lane * 16];
  *(float4*)(lw + 0) = (float4){a0.x * rw, a0.y * rw, a0.z * rw, a0.w * rw};
  *(float4*)(lw + 4) = (float4){a1.x * rw, a1.y * rw, a1.z * rw, a1.w * rw};
  *(float4*)(lw + 8) = (float4){a2.x * rw, a2.y * rw, a2.z * rw, a2.w * rw};
  *(float4*)(lw + 12) = (float4){a3.x * rw, a3.y * rw, a3.z * rw, a3.w * rw};
  __syncthreads();
  float rs = 1.f / Stot;
  // thread t owns dims [t*4, t*4+4)
  float4 p0 = *(const float4*)&lacc[0][t * 4];
  float4 p1 = *(const float4*)&lacc[1][t * 4];
  float4 p2 = *(const float4*)&lacc[2][t * 4];
  float4 p3 = *(const float4*)&lacc[3][t * 4];
  float4 ze;
  ze.x = (p0.x + p1.x + p2.x + p3.x) * rs;
  ze.y = (p0.y + p1.y + p2.y + p3.y) * rs;
  ze.z = (p0.z + p1.z + p2.z + p3.z) * rs;
  ze.w = (p0.w + p1.w + p2.w + p3.w) * rs;
  *(float4*)(z_e + m * 1024 + t * 4) = ze;
  float4 hv = h4[t];
  float4 r;
  r.x = hv.x - ze.x; r.y = hv.y - ze.y; r.z = hv.z - ze.z; r.w = hv.w - ze.w;
  float ss = r.x * r.x + r.y * r.y + r.z * r.z + r.w * r.w;
#pragma unroll
  for (int o = 32; o; o >>= 1) ss += __shfl_xor(ss, o);
  if (lane == 0) sc[wave] = ss;
  __syncthreads();
  float tot = sc[0] + sc[1] + sc[2] + sc[3];
  float inv = 1.f / (sqrtf(tot * (1.f / 1024.f)) + 1e-8f);
  float4 s4 = ((const float4*)scale)[t];
  ushort4 o;
  o.x = f2bf(r.x * inv * s4.x); o.y = f2bf(r.y * inv * s4.y);
  o.z = f2bf(r.z * inv * s4.z); o.w = f2bf(r.w * inv * s4.w);
  *(ushort4*)(x + m * 1024 + t * 4) = o;
}

extern "C" void kernel_launch(void* const* d_in, const int* in_sizes, int n_in,
                              void* d_out, int out_size, void* d_ws, size_t ws_size,
                              hipStream_t stream) {
  const float* h = (const float*)d_in[0];
  const float* cb = (const float*)d_in[1];
  const float* scale = (const float*)d_in[2];
  const float* W = (const float*)d_in[3];
  const float* b = (const float*)d_in[4];
  float* out = (float*)d_out;

  // ws layout (~210 MB total)
  char* ws = (char*)d_ws;
  size_t off = 0;
  auto alloc = [&](size_t bytes) -> char* {
    char* p = ws + off;
    off = (off + bytes + 255) & ~(size_t)255;
    return p;
  };
  s8* h8 = (s8*)alloc(8192L * 1024);            // h i8 (x16)
  s8* c8 = (s8*)alloc(8192L * 1024);            // cb i8 (x16)
  u16* Wbf = (u16*)alloc(1024L * 1024 * 2);     // W bf16
  float* c_sq = (float*)alloc(8192L * 4);
  float* z_e = (float*)alloc(8192L * 1024 * 4); // f32
  u16* x = (u16*)alloc(8192L * 1024 * 2);       // bf16
  int* cand = (int*)alloc(8192L * CAP * 4);     // candidate idx lists
  int* cnt = (int*)alloc(8192L * 4);
  u16* Sbf = (u16*)alloc(8192L * 8192 * 2);     // coarse dist (bf16, offset by 1024)

  prep_h_i8<<<8192, 256, 0, stream>>>(h, h8, 2097152);
  prep_cb_i8<<<8192, 256, 0, stream>>>(cb, c8, c_sq);
  prep_bf16<<<1024, 256, 0, stream>>>(W, Wbf, 262144);

  // coarse dist via i8 MFMA: Sbf = bf16(csq - qh@qc/128 - 1024)
  gemm_c8<<<dim3(64, 64), 256, 0, stream>>>(h8, c8, Sbf, c_sq);
  // per-row min + candidate gather (deterministic ordered compaction)
  scan_rows<<<8192, 256, 0, stream>>>(Sbf, cand, cnt);
  // single-pass online-softmax refine: exact f32, z_e + RMSNorm -> x
  refine_rms<<<8192, 256, 0, stream>>>(h, cb, c_sq, cand, cnt, scale, z_e, x);
  // out = z_e + x @ W^T + b
  gemm_zq<<<dim3(8, 64), 256, 0, stream>>>(x, 1024L, Wbf, 1024L,
                                           out, 1024L, 1024, z_e, b);
}